// Round 11
// baseline (153.841 us; speedup 1.0000x reference)
//
#include <hip/hip_runtime.h>
#include <math.h>

#define W 960
#define NROWS (16 * 544)            // 8704 image rows
#define TPB 256                     // 4 waves; 1 row per wave
#define NBLOCKS (NROWS / 4)         // 2176

typedef float vfloat4 __attribute__((ext_vector_type(4)));

__device__ __forceinline__ float smooth_l1f(float d) {
    float ad = fabsf(d);
    return ad < 1.0f ? 0.5f * d * d : ad - 0.5f;
}

// Wave-private LDS row staging via async DMA (global_load_lds): wave w stages
// row (4*blockIdx+w) into its own segment and is the ONLY reader -> no block
// barrier; a wave-local s_waitcnt vmcnt(0) orders DMA before the gathers.
// Streams (dl/lgt/dlgt) stay on the vmem path -> two request queues in parallel.
__global__ __launch_bounds__(TPB) void loss_kernel(
    const float* __restrict__ dl,
    const float* __restrict__ seg_r,
    const float* __restrict__ dlgt,
    const float* __restrict__ lgt,
    double* __restrict__ ws)
{
    __shared__ float srow[4][W];
    __shared__ double sh[3][4];
    const int tid  = threadIdx.x;
    const int lane = tid & 63;
    const int wave = tid >> 6;
    const int rb   = (blockIdx.x * 4 + wave) * W;   // element base of this wave's row

    // ---- stage own row via DMA: 3 x 1KB (width16) + 3 x 256B (width4) ----
    const float* rsrc = seg_r + rb;
    #pragma unroll
    for (int j = 0; j < 3; ++j) {
        __builtin_amdgcn_global_load_lds(
            (const __attribute__((address_space(1))) void*)(rsrc + j * 256 + lane * 4),
            (__attribute__((address_space(3))) void*)&srow[wave][j * 256],
            16, 0, 0);
    }
    #pragma unroll
    for (int j = 0; j < 3; ++j) {
        __builtin_amdgcn_global_load_lds(
            (const __attribute__((address_space(1))) void*)(rsrc + 768 + j * 64 + lane),
            (__attribute__((address_space(3))) void*)&srow[wave][768 + j * 64],
            4, 0, 0);
    }
    // wave-local drain of the 6 DMAs (no streams issued yet, so this is cheap)
    asm volatile("s_waitcnt vmcnt(0)" ::: "memory");

    const float* __restrict__ srw = srow[wave];
    float cnt = 0.f, s_loss = 0.f, s_recon = 0.f;

    #pragma unroll
    for (int j = 0; j < 15; ++j) {
        int col = lane + 64 * j;                    // strided: all loads share voffset
        float d  = dl  [rb + col];
        float lv = lgt [rb + col];
        float tv = dlgt[rb + col];

        float m = lv > 0.f ? 1.f : 0.f;
        cnt += m;
        s_loss += m * smooth_l1f(d - tv);

        float sx  = (float)col - d;
        float x0f = floorf(sx);
        float wx  = sx - x0f;
        int x0 = (int)x0f;                          // in [-64, 959]
        int xb = min(max(x0, 0), W - 2);
        float p0 = srw[xb];                         // adjacent pair -> ds_read2
        float p1 = srw[xb + 1];
        bool  c  = (x0 == xb);
        float m0 = (x0 >= 0) ? 1.f : 0.f;
        float m1 = (x0 >= -1 && x0 <= W - 2) ? 1.f : 0.f;
        float g0 = (c ? p0 : p1) * m0;
        float g1 = (c ? p1 : p0) * m1;
        float wv = fmaf(wx, g1 - g0, g0);
        float recon = 1.f / (1.f + __expf(-wv));
        s_recon += m * smooth_l1f(recon - lv);
    }

    // ---- block reduction (one barrier, cold path) ----
    double dc = (double)cnt, dlo = (double)s_loss, dre = (double)s_recon;
    for (int off = 32; off > 0; off >>= 1) {
        dc  += __shfl_down(dc,  off, 64);
        dlo += __shfl_down(dlo, off, 64);
        dre += __shfl_down(dre, off, 64);
    }
    if (lane == 0) { sh[0][wave] = dc; sh[1][wave] = dlo; sh[2][wave] = dre; }
    __syncthreads();

    if (tid == 0) {
        double c = 0, l = 0, r = 0;
        #pragma unroll
        for (int j = 0; j < 4; ++j) { c += sh[0][j]; l += sh[1][j]; r += sh[2][j]; }
        double* slot = ws + blockIdx.x * 4;         // plain stores, zero contention
        slot[0] = c; slot[1] = l; slot[2] = r;
    }
}

__global__ __launch_bounds__(256) void finalize_kernel(
    const double* __restrict__ ws, float* __restrict__ out)
{
    double c = 0, l = 0, r = 0;
    for (int i = threadIdx.x; i < NBLOCKS; i += 256) {
        const double* slot = ws + i * 4;
        c += slot[0]; l += slot[1]; r += slot[2];
    }
    for (int off = 32; off > 0; off >>= 1) {
        c += __shfl_down(c, off, 64);
        l += __shfl_down(l, off, 64);
        r += __shfl_down(r, off, 64);
    }
    __shared__ double sh[3][4];
    int lane = threadIdx.x & 63, wid = threadIdx.x >> 6;
    if (lane == 0) { sh[0][wid] = c; sh[1][wid] = l; sh[2][wid] = r; }
    __syncthreads();
    if (threadIdx.x == 0) {
        double cc = 0, ll = 0, rr = 0;
        #pragma unroll
        for (int j = 0; j < 4; ++j) { cc += sh[0][j]; ll += sh[1][j]; rr += sh[2][j]; }
        double loss = ll / cc;
        if (isnan(loss)) loss = 0.0;
        out[0] = (float)(loss + 0.5 * (rr / cc));
    }
}

extern "C" void kernel_launch(void* const* d_in, const int* in_sizes, int n_in,
                              void* d_out, int out_size, void* d_ws, size_t ws_size,
                              hipStream_t stream) {
    const float* dl    = (const float*)d_in[0];
    const float* seg_r = (const float*)d_in[1];
    const float* dlgt  = (const float*)d_in[2];
    const float* lgt   = (const float*)d_in[3];
    double* ws = (double*)d_ws;   // 4 * NBLOCKS doubles; every used slot written each call

    loss_kernel<<<NBLOCKS, TPB, 0, stream>>>(dl, seg_r, dlgt, lgt, ws);
    finalize_kernel<<<1, 256, 0, stream>>>(ws, (float*)d_out);
}

// Round 12
// 148.874 us; speedup vs baseline: 1.0334x; 1.0334x over previous
//
#include <hip/hip_runtime.h>
#include <math.h>

#define W 960
#define NTOT (16 * 544 * 960)
#define N4 (NTOT / 4)               // 2,088,960 float4
#define TPB 256
#define NBLOCKS 2040                // 2040*256*4 == N4 exactly -> uniform 4 iters
#define STRIDE (NBLOCKS * TPB)      // 522,240

typedef float vfloat4 __attribute__((ext_vector_type(4)));

__device__ __forceinline__ float smooth_l1f(float d) {
    float ad = fabsf(d);
    return ad < 1.0f ? 0.5f * d * d : ad - 0.5f;
}

__device__ __forceinline__ void body(
    int i4, vfloat4 d4, vfloat4 l4, vfloat4 t4,
    const float* __restrict__ seg_r,
    float& cnt, float& s_loss, float& s_recon)
{
    int i  = i4 << 2;
    int w0 = i % W;                       // W%4==0: all 4 elems in same row
    const float* __restrict__ row = seg_r + (i - w0);
    #pragma unroll
    for (int k = 0; k < 4; ++k) {
        float lv = l4[k];
        float m = lv > 0.f ? 1.f : 0.f;
        cnt += m;
        float d = d4[k];
        s_loss += m * smooth_l1f(d - t4[k]);

        float sx  = (float)(w0 + k) - d;
        float x0f = floorf(sx);
        float wx  = sx - x0f;
        int x0 = (int)x0f;
        int x1 = x0 + 1;
        float m0 = (x0 >= 0 && x0 < W) ? 1.f : 0.f;
        float m1 = (x1 >= 0 && x1 < W) ? 1.f : 0.f;
        int x0c = min(max(x0, 0), W - 1);
        int x1c = min(max(x1, 0), W - 1);
        float g0 = row[x0c] * m0;          // cached gathers, hot L1/L2 window
        float g1 = row[x1c] * m1;
        float wv = fmaf(wx, g1 - g0, g0);
        float recon = 1.f / (1.f + __expf(-wv));
        s_recon += m * smooth_l1f(recon - lv);
    }
}

// Streaming, barrier-free, uniform-trip, 2x-interleaved fused loss.
__global__ __launch_bounds__(TPB) void loss_kernel(
    const float* __restrict__ dl,
    const float* __restrict__ seg_r,
    const float* __restrict__ dlgt,
    const float* __restrict__ lgt,
    double* __restrict__ ws)
{
    const int tid  = threadIdx.x;
    const int base = blockIdx.x * TPB + tid;
    float cnt = 0.f, s_loss = 0.f, s_recon = 0.f;

    #pragma unroll
    for (int p = 0; p < 4; p += 2) {
        int ia = base + p * STRIDE;
        int ib = base + (p + 1) * STRIDE;
        // issue BOTH points' stream loads before any compute
        vfloat4 da = __builtin_nontemporal_load((const vfloat4*)dl   + ia);
        vfloat4 la = __builtin_nontemporal_load((const vfloat4*)lgt  + ia);
        vfloat4 ta = __builtin_nontemporal_load((const vfloat4*)dlgt + ia);
        vfloat4 db = __builtin_nontemporal_load((const vfloat4*)dl   + ib);
        vfloat4 lb = __builtin_nontemporal_load((const vfloat4*)lgt  + ib);
        vfloat4 tb = __builtin_nontemporal_load((const vfloat4*)dlgt + ib);
        body(ia, da, la, ta, seg_r, cnt, s_loss, s_recon);
        body(ib, db, lb, tb, seg_r, cnt, s_loss, s_recon);
    }

    // block reduction: wave shuffle (double) then LDS across 4 waves
    double dc = (double)cnt, dlo = (double)s_loss, dre = (double)s_recon;
    for (int off = 32; off > 0; off >>= 1) {
        dc  += __shfl_down(dc,  off, 64);
        dlo += __shfl_down(dlo, off, 64);
        dre += __shfl_down(dre, off, 64);
    }
    __shared__ double sh[3][TPB / 64];
    int lane = tid & 63, wid = tid >> 6;
    if (lane == 0) { sh[0][wid] = dc; sh[1][wid] = dlo; sh[2][wid] = dre; }
    __syncthreads();

    if (tid == 0) {
        double c = 0, l = 0, r = 0;
        #pragma unroll
        for (int j = 0; j < TPB / 64; ++j) { c += sh[0][j]; l += sh[1][j]; r += sh[2][j]; }
        double* slot = ws + blockIdx.x * 4;   // plain stores, zero contention
        slot[0] = c; slot[1] = l; slot[2] = r;
    }
}

__global__ __launch_bounds__(256) void finalize_kernel(
    const double* __restrict__ ws, float* __restrict__ out)
{
    double c = 0, l = 0, r = 0;
    for (int i = threadIdx.x; i < NBLOCKS; i += 256) {
        const double* slot = ws + i * 4;
        c += slot[0]; l += slot[1]; r += slot[2];
    }
    for (int off = 32; off > 0; off >>= 1) {
        c += __shfl_down(c, off, 64);
        l += __shfl_down(l, off, 64);
        r += __shfl_down(r, off, 64);
    }
    __shared__ double sh[3][4];
    int lane = threadIdx.x & 63, wid = threadIdx.x >> 6;
    if (lane == 0) { sh[0][wid] = c; sh[1][wid] = l; sh[2][wid] = r; }
    __syncthreads();
    if (threadIdx.x == 0) {
        double cc = 0, ll = 0, rr = 0;
        #pragma unroll
        for (int j = 0; j < 4; ++j) { cc += sh[0][j]; ll += sh[1][j]; rr += sh[2][j]; }
        double loss = ll / cc;
        if (isnan(loss)) loss = 0.0;
        out[0] = (float)(loss + 0.5 * (rr / cc));
    }
}

extern "C" void kernel_launch(void* const* d_in, const int* in_sizes, int n_in,
                              void* d_out, int out_size, void* d_ws, size_t ws_size,
                              hipStream_t stream) {
    const float* dl    = (const float*)d_in[0];
    const float* seg_r = (const float*)d_in[1];
    const float* dlgt  = (const float*)d_in[2];
    const float* lgt   = (const float*)d_in[3];
    double* ws = (double*)d_ws;   // 4 * NBLOCKS doubles; every slot written each call

    loss_kernel<<<NBLOCKS, TPB, 0, stream>>>(dl, seg_r, dlgt, lgt, ws);
    finalize_kernel<<<1, 256, 0, stream>>>(ws, (float*)d_out);
}